// Round 18
// baseline (74.511 us; speedup 1.0000x reference)
//
#include <hip/hip_runtime.h>
#include <hip/hip_bf16.h>

#define B_ 4
#define C_ 256
#define N_ 4096
#define K_ 16
#define FSCALE 1.2011224087864498f   // sqrt(log2(e)) -> QK^T comes out in log2 domain
#define EXPA 8388608.0f              // 2^23
#define EXPB 1065101558.0f           // (127 - 0.030)*2^23  (Schraudolph, balanced +/-3% rel err)

typedef float f32x4 __attribute__((ext_vector_type(4)));
typedef float f32x16 __attribute__((ext_vector_type(16)));
typedef short s16x8 __attribute__((ext_vector_type(8)));
typedef int   i32x4 __attribute__((ext_vector_type(4)));
typedef int   i32x2 __attribute__((ext_vector_type(2)));

__device__ __forceinline__ short f2bf(float f) {
  union { float f; unsigned u; } v; v.f = f;
  unsigned r = v.u + 0x7fffu + ((v.u >> 16) & 1u);
  return (short)(r >> 16);
}
__device__ __forceinline__ int packbf(float a, float b) {
  __hip_bfloat162 h = __float22bfloat162_rn(make_float2(a, b));
  int r; __builtin_memcpy(&r, &h, 4); return r;
}

// ---------------- pass 1 (fused): prep (blocks 0..255) + packv (blocks 256..767) ----------------
__global__ __launch_bounds__(256) void pre(const float* __restrict__ x,
                                           const float* __restrict__ w1,
                                           const float* __restrict__ b1,
                                           short* __restrict__ fT,
                                           short* __restrict__ vtP) {
  __shared__ __align__(16) char sm[20480];
  const int tid = threadIdx.x;
  if (blockIdx.x < 256) {
    float* w1t = (float*)sm;                    // [c][k] 16KB
    __shared__ float pr[4][64][17];
    for (int i = tid; i < C_ * K_; i += 256) {
      int k = i >> 8, c = i & 255;
      w1t[c * K_ + k] = w1[i];
    }
    __syncthreads();
    const int blk = blockIdx.x;
    const int b = blk >> 6;
    const int n0 = (blk & 63) * 64;
    const int nl = tid & 63;
    const int cch = tid >> 6;
    const int n = n0 + nl;
    const float* xp = x + (size_t)b * C_ * N_ + n;
    float acc[K_];
#pragma unroll
    for (int k = 0; k < K_; k++) acc[k] = 0.f;
    for (int cc = 0; cc < 64; cc++) {
      int c = cch * 64 + cc;
      float v = xp[(size_t)c * N_];
      const f32x4* wp = (const f32x4*)(&w1t[c * K_]);
#pragma unroll
      for (int qq = 0; qq < 4; qq++) {
        f32x4 wv = wp[qq];
#pragma unroll
        for (int j = 0; j < 4; j++) acc[qq * 4 + j] += wv[j] * v;
      }
    }
#pragma unroll
    for (int k = 0; k < K_; k++) pr[cch][nl][k] = acc[k];
    __syncthreads();
#pragma unroll
    for (int jj = 0; jj < 4; jj++) {
      int o = tid + jj * 256;
      int on = o >> 4, ok = o & 15;
      float s = pr[0][on][ok] + pr[1][on][ok] + pr[2][on][ok] + pr[3][on][ok] + b1[ok];
      fT[((size_t)b * N_ + n0 + on) * K_ + ok] = f2bf(s * FSCALE);
    }
  } else {
    short* t = (short*)sm;         // [64][136] shorts, XOR-swizzled 8-short blocks
    const int bid = blockIdx.x - 256;   // 512 = 4b x 4cb x 32nb
    const int b = bid >> 7, cb = (bid >> 5) & 3, nb = bid & 31;
    const int n0 = nb * 128, c0 = cb * 64;
    const int r = tid >> 2, cg = tid & 3;
    const float* xp = x + ((size_t)(b * 256 + c0 + r)) * N_ + n0 + cg * 32;
#pragma unroll
    for (int k = 0; k < 8; k++) {
      f32x4 v = *(const f32x4*)(xp + k * 4);
      i32x2 p = {packbf(v[0], v[1]), packbf(v[2], v[3])};
      int col = (cg * 32 + k * 4) ^ ((r & 7) * 8);
      *(i32x2*)(&t[r * 136 + col]) = p;
    }
    __syncthreads();
#pragma unroll
    for (int u = 0; u < 4; u++) {
      int chunk = tid + 256 * u;          // 1024 = 16 gl x 64 c
      int gl = chunk >> 6, c = chunk & 63;
      int m16 = gl >> 1, hi = gl & 1;
      int swz = (c & 7) * 8;
      i32x2 a = *(const i32x2*)(&t[c * 136 + ((m16 * 16 + hi * 4) ^ swz)]);
      i32x2 bq = *(const i32x2*)(&t[c * 136 + ((m16 * 16 + 8 + hi * 4) ^ swz)]);
      i32x4 vv = {a[0], a[1], bq[0], bq[1]};
      size_t g = (size_t)b * 512 + (size_t)(nb * 8 + m16) * 2 + hi;
      *(i32x4*)(vtP + (g * 256 + c0 + c) * 8) = vv;
    }
  }
}

// ---------------- pass 2: drifting 8-wave blocks — shared-P + shared-V, no h-split ----------
// Block = 512 thr (8 waves), covers FULL m for one 32-n column block. Grid 512 = 2 blocks/CU;
// the two blocks have independent barriers and drift, so one block's VALU-heavy production
// overlaps the other's MFMA-heavy PV (the R17 phase-lock stall).
// Per super-iter (512 m): wave u produces P for m-tile mt=u (2 QK MFMA + 32 Schraudolph exp2,
// dedup preserved) -> 4KB LDS -> barrier -> PV over all 8 tiles (32 MFMA, c-span u*32, each V
// fragment loaded once per block) -> barrier. Epilogue: L = 8-wave LDS reduce; out from acc
// directly (no h-merge, no LDS exchange).
__global__ __launch_bounds__(512) void flash14(const float* __restrict__ x,
                                               const short* __restrict__ vtP,
                                               const short* __restrict__ fT,
                                               float* __restrict__ out) {
  __shared__ __align__(16) char lds[34816];   // P 32KB + lrun 2KB
  const int tid = threadIdx.x;
  const int l = tid & 63;
  const int u = tid >> 6;          // 0..7
  const int hi = l >> 5;
  const int q = l & 31;
  const int id = blockIdx.x;
  const int b = id & 3;            // XCD (id&7) -> fixed batch (vtP[b] = 2MB < 4MB L2)
  const int n0 = (id >> 2) * 32;

  const short* fTb = fT + (size_t)b * N_ * K_;

  // Q fragment: n-col = n0 + q (same for all waves of the block)
  const s16x8 qf = *(const s16x8*)(fTb + (size_t)(n0 + q) * K_ + hi * 8);
  // production K rows: m-tile mt=u of each 512-m super-iter
  const short* pkb = fTb + (size_t)(u * 64 + q) * K_ + hi * 8;
  // PV V fragments: c-span u*32; frag m16g at offset m16g*4096 shorts
  const short* pvb = vtP + (((size_t)b * 512 + hi) * 256 + u * 32 + q) * 8;

  char* pwr = lds + u * 4096 + hi * 512 + q * 16;
  const int prdO = hi * 512 + q * 16;

  f32x16 zero16 = {};
  f32x16 acc = zero16;
  float lrun = 0.f;

  for (int si = 0; si < 8; ++si) {
    // ---- produce own P tile (mt = u): m in [si*512 + u*64, +64) ----
    const short* pk = pkb + (size_t)si * 512 * K_;
    s16x8 kf0 = *(const s16x8*)(pk);
    s16x8 kf1 = *(const s16x8*)(pk + 32 * K_);

    __builtin_amdgcn_s_setprio(1);
    f32x16 st0 = __builtin_amdgcn_mfma_f32_32x32x16_bf16(kf0, qf, zero16, 0, 0, 0);
    f32x16 st1 = __builtin_amdgcn_mfma_f32_32x32x16_bf16(kf1, qf, zero16, 0, 0, 0);

    int sd0[8], sd1[8];
    float ps0 = 0.f, ps1 = 0.f, ps2 = 0.f, ps3 = 0.f;
#pragma unroll
    for (int s2 = 0; s2 < 8; s2++) {
      int ia = (int)(st0[2 * s2] * EXPA + EXPB);
      int ib = (int)(st0[2 * s2 + 1] * EXPA + EXPB);
      ps0 += __int_as_float(ia);
      ps1 += __int_as_float(ib);
      sd0[s2] = (int)__builtin_amdgcn_perm((unsigned)ib, (unsigned)ia, 0x07060302u);
    }
#pragma unroll
    for (int s2 = 0; s2 < 8; s2++) {
      int ia = (int)(st1[2 * s2] * EXPA + EXPB);
      int ib = (int)(st1[2 * s2 + 1] * EXPA + EXPB);
      ps2 += __int_as_float(ia);
      ps3 += __int_as_float(ib);
      sd1[s2] = (int)__builtin_amdgcn_perm((unsigned)ib, (unsigned)ia, 0x07060302u);
    }
    lrun += (ps0 + ps1) + (ps2 + ps3);
    __builtin_amdgcn_s_setprio(0);

    *(i32x4*)(pwr)        = (i32x4){sd0[0], sd0[1], sd0[2], sd0[3]};
    *(i32x4*)(pwr + 1024) = (i32x4){sd0[4], sd0[5], sd0[6], sd0[7]};
    *(i32x4*)(pwr + 2048) = (i32x4){sd1[0], sd1[1], sd1[2], sd1[3]};
    *(i32x4*)(pwr + 3072) = (i32x4){sd1[4], sd1[5], sd1[6], sd1[7]};
    __syncthreads();

    // ---- PV over the 8 shared tiles (512 m): 32 MFMA, V loaded once per fragment ----
    __builtin_amdgcn_s_setprio(1);
#pragma unroll
    for (int mt = 0; mt < 8; ++mt) {
      const short* pv = pvb + (size_t)(si * 32 + mt * 4) * 4096;
      s16x8 vA0 = *(const s16x8*)(pv);
      s16x8 vA1 = *(const s16x8*)(pv + 4096);
      s16x8 vA2 = *(const s16x8*)(pv + 8192);
      s16x8 vA3 = *(const s16x8*)(pv + 12288);
      const char* prd = lds + mt * 4096 + prdO;
      s16x8 pf0 = __builtin_bit_cast(s16x8, *(const i32x4*)(prd));
      s16x8 pf1 = __builtin_bit_cast(s16x8, *(const i32x4*)(prd + 1024));
      s16x8 pf2 = __builtin_bit_cast(s16x8, *(const i32x4*)(prd + 2048));
      s16x8 pf3 = __builtin_bit_cast(s16x8, *(const i32x4*)(prd + 3072));
      acc = __builtin_amdgcn_mfma_f32_32x32x16_bf16(vA0, pf0, acc, 0, 0, 0);
      acc = __builtin_amdgcn_mfma_f32_32x32x16_bf16(vA1, pf1, acc, 0, 0, 0);
      acc = __builtin_amdgcn_mfma_f32_32x32x16_bf16(vA2, pf2, acc, 0, 0, 0);
      acc = __builtin_amdgcn_mfma_f32_32x32x16_bf16(vA3, pf3, acc, 0, 0, 0);
    }
    __builtin_amdgcn_s_setprio(0);
    __syncthreads();
  }

  // hi-partner combine of own-tile column sums
  lrun += __shfl_xor(lrun, 32);

  // ---------------- epilogue: L = 8-wave reduce; out written directly from acc ----------------
  float* mlb = (float*)(lds + 32768);   // [8 waves][64 lanes]
  mlb[u * 64 + l] = lrun;
  __syncthreads();
  float L = 0.f;
#pragma unroll
  for (int uu = 0; uu < 8; ++uu) L += mlb[uu * 64 + q];
  const float inv = 0.1f / L;
  const int n = n0 + q;
#pragma unroll
  for (int r = 0; r < 16; ++r) {
    const int c = u * 32 + (r & 3) + 8 * (r >> 2) + 4 * hi;
    const size_t idx = ((size_t)b * C_ + c) * N_ + n;
    out[idx] = x[idx] + acc[r] * inv;
  }
}

extern "C" void kernel_launch(void* const* d_in, const int* in_sizes, int n_in,
                              void* d_out, int out_size, void* d_ws, size_t ws_size,
                              hipStream_t stream) {
  const float* x  = (const float*)d_in[0];
  const float* w1 = (const float*)d_in[1];
  const float* b1 = (const float*)d_in[2];
  float* out = (float*)d_out;
  short* fT  = (short*)d_ws;                         // [B][N][16] bf16, 512KB
  short* vtP = (short*)((char*)d_ws + 512 * 1024);   // [B][512][256][8] bf16, 8MB
  pre<<<dim3(768), dim3(256), 0, stream>>>(x, w1, b1, fT, vtP);
  flash14<<<dim3(512), dim3(512), 0, stream>>>(x, vtP, fT, out);
}

// Round 19
// 61.405 us; speedup vs baseline: 1.2134x; 1.2134x over previous
//
#include <hip/hip_runtime.h>
#include <hip/hip_bf16.h>

#define B_ 4
#define C_ 256
#define N_ 4096
#define K_ 16
#define QB 64
#define FSCALE 1.2011224087864498f   // sqrt(log2(e)) -> QK^T comes out in log2 domain
#define EXPA 8388608.0f              // 2^23
#define EXPB 1065101558.0f           // (127 - 0.030)*2^23  (Schraudolph, balanced +/-3% rel err)

typedef float f32x4 __attribute__((ext_vector_type(4)));
typedef float f32x16 __attribute__((ext_vector_type(16)));
typedef short s16x8 __attribute__((ext_vector_type(8)));
typedef int   i32x4 __attribute__((ext_vector_type(4)));
typedef int   i32x2 __attribute__((ext_vector_type(2)));

__device__ __forceinline__ short f2bf(float f) {
  union { float f; unsigned u; } v; v.f = f;
  unsigned r = v.u + 0x7fffu + ((v.u >> 16) & 1u);
  return (short)(r >> 16);
}
__device__ __forceinline__ int packbf(float a, float b) {
  __hip_bfloat162 h = __float22bfloat162_rn(make_float2(a, b));
  int r; __builtin_memcpy(&r, &h, 4); return r;
}

// ---------------- pass 1 (fused): prep (blocks 0..511, 32 cols each) + packv (512..1023) -------
// prep rebalanced to 512 blocks so the two roles finish together (tail removal).
__global__ __launch_bounds__(256) void pre(const float* __restrict__ x,
                                           const float* __restrict__ w1,
                                           const float* __restrict__ b1,
                                           short* __restrict__ fT,
                                           short* __restrict__ vtP) {
  __shared__ __align__(16) char sm[20480];
  const int tid = threadIdx.x;
  if (blockIdx.x < 512) {
    float* w1t = (float*)sm;                    // [c][k] 16KB
    __shared__ float pr[8][32][17];             // 17.4KB
    for (int i = tid; i < C_ * K_; i += 256) {
      int k = i >> 8, c = i & 255;
      w1t[c * K_ + k] = w1[i];
    }
    __syncthreads();
    const int blk = blockIdx.x;
    const int b = blk >> 7;
    const int n0 = (blk & 127) * 32;
    const int nl = tid & 31;
    const int cch = tid >> 5;       // 0..7, 32 c each
    const int n = n0 + nl;
    const float* xp = x + (size_t)b * C_ * N_ + n;
    float acc[K_];
#pragma unroll
    for (int k = 0; k < K_; k++) acc[k] = 0.f;
    for (int cc = 0; cc < 32; cc++) {
      int c = cch * 32 + cc;
      float v = xp[(size_t)c * N_];
      const f32x4* wp = (const f32x4*)(&w1t[c * K_]);
#pragma unroll
      for (int qq = 0; qq < 4; qq++) {
        f32x4 wv = wp[qq];
#pragma unroll
        for (int j = 0; j < 4; j++) acc[qq * 4 + j] += wv[j] * v;
      }
    }
#pragma unroll
    for (int k = 0; k < K_; k++) pr[cch][nl][k] = acc[k];
    __syncthreads();
#pragma unroll
    for (int jj = 0; jj < 2; jj++) {
      int o = tid + jj * 256;       // 512 outputs = 32n x 16k
      int on = o >> 4, ok = o & 15;
      float s = b1[ok];
#pragma unroll
      for (int u = 0; u < 8; u++) s += pr[u][on][ok];
      fT[((size_t)b * N_ + n0 + on) * K_ + ok] = f2bf(s * FSCALE);
    }
  } else {
    short* t = (short*)sm;         // [64][136] shorts, XOR-swizzled 8-short blocks
    const int bid = blockIdx.x - 512;   // 512 = 4b x 4cb x 32nb
    const int b = bid >> 7, cb = (bid >> 5) & 3, nb = bid & 31;
    const int n0 = nb * 128, c0 = cb * 64;
    const int r = tid >> 2, cg = tid & 3;
    const float* xp = x + ((size_t)(b * 256 + c0 + r)) * N_ + n0 + cg * 32;
#pragma unroll
    for (int k = 0; k < 8; k++) {
      f32x4 v = *(const f32x4*)(xp + k * 4);
      i32x2 p = {packbf(v[0], v[1]), packbf(v[2], v[3])};
      int col = (cg * 32 + k * 4) ^ ((r & 7) * 8);
      *(i32x2*)(&t[r * 136 + col]) = p;
    }
    __syncthreads();
#pragma unroll
    for (int u = 0; u < 4; u++) {
      int chunk = tid + 256 * u;          // 1024 = 16 gl x 64 c
      int gl = chunk >> 6, c = chunk & 63;
      int m16 = gl >> 1, hi = gl & 1;
      int swz = (c & 7) * 8;
      i32x2 a = *(const i32x2*)(&t[c * 136 + ((m16 * 16 + hi * 4) ^ swz)]);
      i32x2 bq = *(const i32x2*)(&t[c * 136 + ((m16 * 16 + 8 + hi * 4) ^ swz)]);
      i32x4 vv = {a[0], a[1], bq[0], bq[1]};
      size_t g = (size_t)b * 512 + (size_t)(nb * 8 + m16) * 2 + hi;
      *(i32x4*)(vtP + (g * 256 + c0 + c) * 8) = vv;
    }
  }
}

// ---------------- pass 2: R17 flash13 (proven 53.5us) + cross-barrier K-rotation ----------
// 16 waves = h(2) x u(8). Production: (mt_p=u>>1, nt_p=u&1) one 64m x 32n P-tile per wave.
// PV: c-span u*32, BOTH nt (V loaded once). New vs R17: next si's K fragments are loaded right
// after QK and carried in registers across both barriers (compiler cannot hoist loads across
// __syncthreads; this removes the ~600cy exposed K latency at each production start).
__global__ __launch_bounds__(1024) void flash16(const float* __restrict__ x,
                                                const short* __restrict__ vtP,
                                                const short* __restrict__ fT,
                                                float* __restrict__ out) {
  __shared__ __align__(16) char lds[65536];
  const int tid = threadIdx.x;
  const int l = tid & 63;
  const int w = tid >> 6;
  const int h = w >> 3;
  const int u = w & 7;
  const int mt_p = u >> 1;
  const int nt_p = u & 1;
  const int hi = l >> 5;
  const int q = l & 31;
  const int id = blockIdx.x;
  const int b = id & 3;            // XCD (id&7) -> fixed batch (vtP[b] = 2MB < 4MB L2)
  const int n0 = (id >> 2) * QB;

  const short* fTb = fT + (size_t)b * N_ * K_;
  const int mh0 = h * 2048;

  const s16x8 qf = *(const s16x8*)(fTb + (size_t)(n0 + nt_p * 32 + q) * K_ + hi * 8);
  const short* pkb = fTb + (size_t)(mh0 + mt_p * 64 + q) * K_ + hi * 8;
  const short* pvb = vtP + (((size_t)b * 512 + (mh0 >> 4) * 2 + hi) * 256 + u * 32 + q) * 8;

  char* pwr = lds + ((h * 2 + nt_p) * 4 + mt_p) * 4096 + hi * 512 + q * 16;
  const int prdO = hi * 512 + q * 16;

  f32x16 zero16 = {};
  f32x16 acc0 = zero16, acc1 = zero16;   // acc0 = nt0, acc1 = nt1 (same 32-c span)
  float lrun = 0.f;

  // prologue K for si=0
  s16x8 kf0 = *(const s16x8*)(pkb);
  s16x8 kf1 = *(const s16x8*)(pkb + 32 * K_);

  for (int si = 0; si < 8; ++si) {
    __builtin_amdgcn_s_setprio(1);
    f32x16 st0 = __builtin_amdgcn_mfma_f32_32x32x16_bf16(kf0, qf, zero16, 0, 0, 0);
    f32x16 st1 = __builtin_amdgcn_mfma_f32_32x32x16_bf16(kf1, qf, zero16, 0, 0, 0);

    // cross-barrier K prefetch for si+1 (clamped; last iter re-reads tile 7, discarded)
    const short* pkn = pkb + (size_t)((si < 7 ? si + 1 : 7) * 256) * K_;
    s16x8 nk0 = *(const s16x8*)(pkn);
    s16x8 nk1 = *(const s16x8*)(pkn + 32 * K_);

    int sd0[8], sd1[8];
    float ps0 = 0.f, ps1 = 0.f, ps2 = 0.f, ps3 = 0.f;
#pragma unroll
    for (int s2 = 0; s2 < 8; s2++) {
      int ia = (int)(st0[2 * s2] * EXPA + EXPB);
      int ib = (int)(st0[2 * s2 + 1] * EXPA + EXPB);
      ps0 += __int_as_float(ia);
      ps1 += __int_as_float(ib);
      sd0[s2] = (int)__builtin_amdgcn_perm((unsigned)ib, (unsigned)ia, 0x07060302u);
    }
#pragma unroll
    for (int s2 = 0; s2 < 8; s2++) {
      int ia = (int)(st1[2 * s2] * EXPA + EXPB);
      int ib = (int)(st1[2 * s2 + 1] * EXPA + EXPB);
      ps2 += __int_as_float(ia);
      ps3 += __int_as_float(ib);
      sd1[s2] = (int)__builtin_amdgcn_perm((unsigned)ib, (unsigned)ia, 0x07060302u);
    }
    lrun += (ps0 + ps1) + (ps2 + ps3);
    __builtin_amdgcn_s_setprio(0);

    *(i32x4*)(pwr)        = (i32x4){sd0[0], sd0[1], sd0[2], sd0[3]};
    *(i32x4*)(pwr + 1024) = (i32x4){sd0[4], sd0[5], sd0[6], sd0[7]};
    *(i32x4*)(pwr + 2048) = (i32x4){sd1[0], sd1[1], sd1[2], sd1[3]};
    *(i32x4*)(pwr + 3072) = (i32x4){sd1[4], sd1[5], sd1[6], sd1[7]};
    __syncthreads();

    // ---- PV: V loaded once per (mt,m16), applied to both nt's P ----
    __builtin_amdgcn_s_setprio(1);
#pragma unroll
    for (int mt = 0; mt < 4; ++mt) {
      const short* pv = pvb + (size_t)(si * 4 + mt) * 16384;
      s16x8 vA0 = *(const s16x8*)(pv);
      s16x8 vA1 = *(const s16x8*)(pv + 4096);
      s16x8 vA2 = *(const s16x8*)(pv + 8192);
      s16x8 vA3 = *(const s16x8*)(pv + 12288);
      const char* p0 = lds + ((h * 2 + 0) * 4 + mt) * 4096 + prdO;
      const char* p1 = lds + ((h * 2 + 1) * 4 + mt) * 4096 + prdO;
      s16x8 pa0 = __builtin_bit_cast(s16x8, *(const i32x4*)(p0));
      s16x8 pb0 = __builtin_bit_cast(s16x8, *(const i32x4*)(p1));
      acc0 = __builtin_amdgcn_mfma_f32_32x32x16_bf16(vA0, pa0, acc0, 0, 0, 0);
      acc1 = __builtin_amdgcn_mfma_f32_32x32x16_bf16(vA0, pb0, acc1, 0, 0, 0);
      s16x8 pa1 = __builtin_bit_cast(s16x8, *(const i32x4*)(p0 + 1024));
      s16x8 pb1 = __builtin_bit_cast(s16x8, *(const i32x4*)(p1 + 1024));
      acc0 = __builtin_amdgcn_mfma_f32_32x32x16_bf16(vA1, pa1, acc0, 0, 0, 0);
      acc1 = __builtin_amdgcn_mfma_f32_32x32x16_bf16(vA1, pb1, acc1, 0, 0, 0);
      s16x8 pa2 = __builtin_bit_cast(s16x8, *(const i32x4*)(p0 + 2048));
      s16x8 pb2 = __builtin_bit_cast(s16x8, *(const i32x4*)(p1 + 2048));
      acc0 = __builtin_amdgcn_mfma_f32_32x32x16_bf16(vA2, pa2, acc0, 0, 0, 0);
      acc1 = __builtin_amdgcn_mfma_f32_32x32x16_bf16(vA2, pb2, acc1, 0, 0, 0);
      s16x8 pa3 = __builtin_bit_cast(s16x8, *(const i32x4*)(p0 + 3072));
      s16x8 pb3 = __builtin_bit_cast(s16x8, *(const i32x4*)(p1 + 3072));
      acc0 = __builtin_amdgcn_mfma_f32_32x32x16_bf16(vA3, pa3, acc0, 0, 0, 0);
      acc1 = __builtin_amdgcn_mfma_f32_32x32x16_bf16(vA3, pb3, acc1, 0, 0, 0);
    }
    __builtin_amdgcn_s_setprio(0);
    __syncthreads();

    kf0 = nk0; kf1 = nk1;
  }

  // hi-partner combine of own-tile column sums
  lrun += __shfl_xor(lrun, 32);

  // ---------------- epilogue ----------------
  float* mlb = (float*)lds;             // [16 waves][64 lanes] (P no longer needed)
  mlb[w * 64 + l] = lrun;
  __syncthreads();
  float L0 = 0.f, L1 = 0.f;
#pragma unroll
  for (int hh = 0; hh < 2; ++hh)
#pragma unroll
    for (int mt = 0; mt < 4; ++mt) {
      L0 += mlb[(hh * 8 + mt * 2 + 0) * 64 + l];
      L1 += mlb[(hh * 8 + mt * 2 + 1) * 64 + l];
    }
  __syncthreads();
  char* xch = lds;                      // [8 u][64 l][128B], swizzled
  const int xbase = (u * 64 + l) * 128;
  if (h == 1) {
#pragma unroll
    for (int i = 0; i < 8; i++) {
      f32x4 v;
#pragma unroll
      for (int r = 0; r < 4; r++) v[r] = (i >> 2) ? acc1[(i & 3) * 4 + r] : acc0[(i & 3) * 4 + r];
      *(f32x4*)(xch + xbase + ((i * 16) ^ ((l & 7) << 4))) = v;
    }
  }
  __syncthreads();
  if (h == 0) {
    const float inv0 = 0.1f / L0;
    const float inv1 = 0.1f / L1;
#pragma unroll
    for (int i = 0; i < 8; i++) {
      f32x4 po = *(const f32x4*)(xch + xbase + ((i * 16) ^ ((l & 7) << 4)));
      const int p_ = i & 3;
      const int ntw = i >> 2;
      const float inv = ntw ? inv1 : inv0;
      const int n = n0 + ntw * 32 + q;
      const int cbase = u * 32 + p_ * 8 + hi * 4;
#pragma unroll
      for (int r = 0; r < 4; r++) {
        const float own = ntw ? acc1[p_ * 4 + r] : acc0[p_ * 4 + r];
        const size_t idx = ((size_t)b * C_ + (cbase + r)) * N_ + n;
        out[idx] = x[idx] + (own + po[r]) * inv;
      }
    }
  }
}

extern "C" void kernel_launch(void* const* d_in, const int* in_sizes, int n_in,
                              void* d_out, int out_size, void* d_ws, size_t ws_size,
                              hipStream_t stream) {
  const float* x  = (const float*)d_in[0];
  const float* w1 = (const float*)d_in[1];
  const float* b1 = (const float*)d_in[2];
  float* out = (float*)d_out;
  short* fT  = (short*)d_ws;                         // [B][N][16] bf16, 512KB
  short* vtP = (short*)((char*)d_ws + 512 * 1024);   // [B][512][256][8] bf16, 8MB
  pre<<<dim3(1024), dim3(256), 0, stream>>>(x, w1, b1, fT, vtP);
  flash16<<<dim3(256), dim3(1024), 0, stream>>>(x, vtP, fT, out);
}

// Round 20
// 61.375 us; speedup vs baseline: 1.2140x; 1.0005x over previous
//
#include <hip/hip_runtime.h>
#include <hip/hip_bf16.h>

#define B_ 4
#define C_ 256
#define N_ 4096
#define K_ 16
#define QB 64
#define FSCALE 1.2011224087864498f   // sqrt(log2(e)) -> QK^T comes out in log2 domain
#define EXPA 8388608.0f              // 2^23
#define EXPB 1065101558.0f           // (127 - 0.030)*2^23  (Schraudolph, balanced +/-3% rel err)

typedef float f32x4 __attribute__((ext_vector_type(4)));
typedef float f32x16 __attribute__((ext_vector_type(16)));
typedef short s16x8 __attribute__((ext_vector_type(8)));
typedef int   i32x4 __attribute__((ext_vector_type(4)));
typedef int   i32x2 __attribute__((ext_vector_type(2)));

__device__ __forceinline__ short f2bf(float f) {
  union { float f; unsigned u; } v; v.f = f;
  unsigned r = v.u + 0x7fffu + ((v.u >> 16) & 1u);
  return (short)(r >> 16);
}
__device__ __forceinline__ int packbf(float a, float b) {
  __hip_bfloat162 h = __float22bfloat162_rn(make_float2(a, b));
  int r; __builtin_memcpy(&r, &h, 4); return r;
}

// ---------------- pass 1 (fused): prep (blocks 0..511, 32 cols each) + packv (512..1023) -------
__global__ __launch_bounds__(256) void pre(const float* __restrict__ x,
                                           const float* __restrict__ w1,
                                           const float* __restrict__ b1,
                                           short* __restrict__ fT,
                                           short* __restrict__ vtP) {
  __shared__ __align__(16) char sm[20480];
  const int tid = threadIdx.x;
  if (blockIdx.x < 512) {
    float* w1t = (float*)sm;                    // [c][k] 16KB
    __shared__ float pr[8][32][17];             // 17.4KB
    for (int i = tid; i < C_ * K_; i += 256) {
      int k = i >> 8, c = i & 255;
      w1t[c * K_ + k] = w1[i];
    }
    __syncthreads();
    const int blk = blockIdx.x;
    const int b = blk >> 7;
    const int n0 = (blk & 127) * 32;
    const int nl = tid & 31;
    const int cch = tid >> 5;       // 0..7, 32 c each
    const int n = n0 + nl;
    const float* xp = x + (size_t)b * C_ * N_ + n;
    float acc[K_];
#pragma unroll
    for (int k = 0; k < K_; k++) acc[k] = 0.f;
    for (int cc = 0; cc < 32; cc++) {
      int c = cch * 32 + cc;
      float v = xp[(size_t)c * N_];
      const f32x4* wp = (const f32x4*)(&w1t[c * K_]);
#pragma unroll
      for (int qq = 0; qq < 4; qq++) {
        f32x4 wv = wp[qq];
#pragma unroll
        for (int j = 0; j < 4; j++) acc[qq * 4 + j] += wv[j] * v;
      }
    }
#pragma unroll
    for (int k = 0; k < K_; k++) pr[cch][nl][k] = acc[k];
    __syncthreads();
#pragma unroll
    for (int jj = 0; jj < 2; jj++) {
      int o = tid + jj * 256;       // 512 outputs = 32n x 16k
      int on = o >> 4, ok = o & 15;
      float s = b1[ok];
#pragma unroll
      for (int u = 0; u < 8; u++) s += pr[u][on][ok];
      fT[((size_t)b * N_ + n0 + on) * K_ + ok] = f2bf(s * FSCALE);
    }
  } else {
    short* t = (short*)sm;         // [64][136] shorts, XOR-swizzled 8-short blocks
    const int bid = blockIdx.x - 512;   // 512 = 4b x 4cb x 32nb
    const int b = bid >> 7, cb = (bid >> 5) & 3, nb = bid & 31;
    const int n0 = nb * 128, c0 = cb * 64;
    const int r = tid >> 2, cg = tid & 3;
    const float* xp = x + ((size_t)(b * 256 + c0 + r)) * N_ + n0 + cg * 32;
#pragma unroll
    for (int k = 0; k < 8; k++) {
      f32x4 v = *(const f32x4*)(xp + k * 4);
      i32x2 p = {packbf(v[0], v[1]), packbf(v[2], v[3])};
      int col = (cg * 32 + k * 4) ^ ((r & 7) * 8);
      *(i32x2*)(&t[r * 136 + col]) = p;
    }
    __syncthreads();
#pragma unroll
    for (int u = 0; u < 4; u++) {
      int chunk = tid + 256 * u;          // 1024 = 16 gl x 64 c
      int gl = chunk >> 6, c = chunk & 63;
      int m16 = gl >> 1, hi = gl & 1;
      int swz = (c & 7) * 8;
      i32x2 a = *(const i32x2*)(&t[c * 136 + ((m16 * 16 + hi * 4) ^ swz)]);
      i32x2 bq = *(const i32x2*)(&t[c * 136 + ((m16 * 16 + 8 + hi * 4) ^ swz)]);
      i32x4 vv = {a[0], a[1], bq[0], bq[1]};
      size_t g = (size_t)b * 512 + (size_t)(nb * 8 + m16) * 2 + hi;
      *(i32x4*)(vtP + (g * 256 + c0 + c) * 8) = vv;
    }
  }
}

// ---------------- pass 2: R17/R19 structure + IN-WAVE producer/consumer overlap --------------
// 16 waves = h(2) x u(8); production (mt_p=u>>1, nt_p=u&1); PV c-span u*32 both nt.
// Key change: produce P(si+1) IN REGISTERS inside the same scheduling region as PV(si) — the
// exp/pack VALU chain and QK MFMAs interleave into PV's matrix-pipe shadow (phase-lock removal).
// Then: barrier (PV done reading P(si)) -> write sd -> barrier. Last iter produces a clamped
// dummy (lsc=0 for lrun; its write is never read). K register-rotated one iter ahead (R19).
__global__ __launch_bounds__(1024) void flash17(const float* __restrict__ x,
                                                const short* __restrict__ vtP,
                                                const short* __restrict__ fT,
                                                float* __restrict__ out) {
  __shared__ __align__(16) char lds[65536];
  const int tid = threadIdx.x;
  const int l = tid & 63;
  const int w = tid >> 6;
  const int h = w >> 3;
  const int u = w & 7;
  const int mt_p = u >> 1;
  const int nt_p = u & 1;
  const int hi = l >> 5;
  const int q = l & 31;
  const int id = blockIdx.x;
  const int b = id & 3;            // XCD (id&7) -> fixed batch (vtP[b] = 2MB < 4MB L2)
  const int n0 = (id >> 2) * QB;

  const short* fTb = fT + (size_t)b * N_ * K_;
  const int mh0 = h * 2048;

  const s16x8 qf = *(const s16x8*)(fTb + (size_t)(n0 + nt_p * 32 + q) * K_ + hi * 8);
  const short* pkb = fTb + (size_t)(mh0 + mt_p * 64 + q) * K_ + hi * 8;
  const short* pvb = vtP + (((size_t)b * 512 + (mh0 >> 4) * 2 + hi) * 256 + u * 32 + q) * 8;

  char* pwr = lds + ((h * 2 + nt_p) * 4 + mt_p) * 4096 + hi * 512 + q * 16;
  const int prdO = hi * 512 + q * 16;

  f32x16 zero16 = {};
  f32x16 acc0 = zero16, acc1 = zero16;   // acc0 = nt0, acc1 = nt1 (same 32-c span)
  float lrun = 0.f;

  // ---- prologue: produce P(0), write, bar ----
  {
    s16x8 k0 = *(const s16x8*)(pkb);
    s16x8 k1 = *(const s16x8*)(pkb + 32 * K_);
    f32x16 st0 = __builtin_amdgcn_mfma_f32_32x32x16_bf16(k0, qf, zero16, 0, 0, 0);
    f32x16 st1 = __builtin_amdgcn_mfma_f32_32x32x16_bf16(k1, qf, zero16, 0, 0, 0);
    int sd0[8], sd1[8];
    float ps0 = 0.f, ps1 = 0.f, ps2 = 0.f, ps3 = 0.f;
#pragma unroll
    for (int s2 = 0; s2 < 8; s2++) {
      int ia = (int)(st0[2 * s2] * EXPA + EXPB);
      int ib = (int)(st0[2 * s2 + 1] * EXPA + EXPB);
      ps0 += __int_as_float(ia);
      ps1 += __int_as_float(ib);
      sd0[s2] = (int)__builtin_amdgcn_perm((unsigned)ib, (unsigned)ia, 0x07060302u);
    }
#pragma unroll
    for (int s2 = 0; s2 < 8; s2++) {
      int ia = (int)(st1[2 * s2] * EXPA + EXPB);
      int ib = (int)(st1[2 * s2 + 1] * EXPA + EXPB);
      ps2 += __int_as_float(ia);
      ps3 += __int_as_float(ib);
      sd1[s2] = (int)__builtin_amdgcn_perm((unsigned)ib, (unsigned)ia, 0x07060302u);
    }
    lrun += (ps0 + ps1) + (ps2 + ps3);
    *(i32x4*)(pwr)        = (i32x4){sd0[0], sd0[1], sd0[2], sd0[3]};
    *(i32x4*)(pwr + 1024) = (i32x4){sd0[4], sd0[5], sd0[6], sd0[7]};
    *(i32x4*)(pwr + 2048) = (i32x4){sd1[0], sd1[1], sd1[2], sd1[3]};
    *(i32x4*)(pwr + 3072) = (i32x4){sd1[4], sd1[5], sd1[6], sd1[7]};
  }
  __syncthreads();
  // K for production of P(1)
  s16x8 kf0 = *(const s16x8*)(pkb + 256 * K_);
  s16x8 kf1 = *(const s16x8*)(pkb + 256 * K_ + 32 * K_);

  for (int si = 0; si < 8; ++si) {
    const float lsc = (si < 7) ? 1.f : 0.f;
    const short* pkn = pkb + (size_t)((si + 2 < 7 ? si + 2 : 7) * 256) * K_;

    __builtin_amdgcn_s_setprio(1);

    // ---- production of P(si+1) in registers (clamped dummy at si=7) ----
    f32x16 st0 = __builtin_amdgcn_mfma_f32_32x32x16_bf16(kf0, qf, zero16, 0, 0, 0);
    f32x16 st1 = __builtin_amdgcn_mfma_f32_32x32x16_bf16(kf1, qf, zero16, 0, 0, 0);
    s16x8 nk0 = *(const s16x8*)(pkn);
    s16x8 nk1 = *(const s16x8*)(pkn + 32 * K_);
    int sd0[8], sd1[8];
    float ps0 = 0.f, ps1 = 0.f, ps2 = 0.f, ps3 = 0.f;
#pragma unroll
    for (int s2 = 0; s2 < 8; s2++) {
      int ia = (int)(st0[2 * s2] * EXPA + EXPB);
      int ib = (int)(st0[2 * s2 + 1] * EXPA + EXPB);
      ps0 += __int_as_float(ia);
      ps1 += __int_as_float(ib);
      sd0[s2] = (int)__builtin_amdgcn_perm((unsigned)ib, (unsigned)ia, 0x07060302u);
    }
#pragma unroll
    for (int s2 = 0; s2 < 8; s2++) {
      int ia = (int)(st1[2 * s2] * EXPA + EXPB);
      int ib = (int)(st1[2 * s2 + 1] * EXPA + EXPB);
      ps2 += __int_as_float(ia);
      ps3 += __int_as_float(ib);
      sd1[s2] = (int)__builtin_amdgcn_perm((unsigned)ib, (unsigned)ia, 0x07060302u);
    }
    lrun += lsc * ((ps0 + ps1) + (ps2 + ps3));

    // ---- PV(si): V loaded once per (mt,m16), applied to both nt's P — same region, so the
    // compiler interleaves these MFMAs with the exp/pack VALU above ----
#pragma unroll
    for (int mt = 0; mt < 4; ++mt) {
      const short* pv = pvb + (size_t)(si * 4 + mt) * 16384;
      s16x8 vA0 = *(const s16x8*)(pv);
      s16x8 vA1 = *(const s16x8*)(pv + 4096);
      s16x8 vA2 = *(const s16x8*)(pv + 8192);
      s16x8 vA3 = *(const s16x8*)(pv + 12288);
      const char* p0 = lds + ((h * 2 + 0) * 4 + mt) * 4096 + prdO;
      const char* p1 = lds + ((h * 2 + 1) * 4 + mt) * 4096 + prdO;
      s16x8 pa0 = __builtin_bit_cast(s16x8, *(const i32x4*)(p0));
      s16x8 pb0 = __builtin_bit_cast(s16x8, *(const i32x4*)(p1));
      acc0 = __builtin_amdgcn_mfma_f32_32x32x16_bf16(vA0, pa0, acc0, 0, 0, 0);
      acc1 = __builtin_amdgcn_mfma_f32_32x32x16_bf16(vA0, pb0, acc1, 0, 0, 0);
      s16x8 pa1 = __builtin_bit_cast(s16x8, *(const i32x4*)(p0 + 1024));
      s16x8 pb1 = __builtin_bit_cast(s16x8, *(const i32x4*)(p1 + 1024));
      acc0 = __builtin_amdgcn_mfma_f32_32x32x16_bf16(vA1, pa1, acc0, 0, 0, 0);
      acc1 = __builtin_amdgcn_mfma_f32_32x32x16_bf16(vA1, pb1, acc1, 0, 0, 0);
      s16x8 pa2 = __builtin_bit_cast(s16x8, *(const i32x4*)(p0 + 2048));
      s16x8 pb2 = __builtin_bit_cast(s16x8, *(const i32x4*)(p1 + 2048));
      acc0 = __builtin_amdgcn_mfma_f32_32x32x16_bf16(vA2, pa2, acc0, 0, 0, 0);
      acc1 = __builtin_amdgcn_mfma_f32_32x32x16_bf16(vA2, pb2, acc1, 0, 0, 0);
      s16x8 pa3 = __builtin_bit_cast(s16x8, *(const i32x4*)(p0 + 3072));
      s16x8 pb3 = __builtin_bit_cast(s16x8, *(const i32x4*)(p1 + 3072));
      acc0 = __builtin_amdgcn_mfma_f32_32x32x16_bf16(vA3, pa3, acc0, 0, 0, 0);
      acc1 = __builtin_amdgcn_mfma_f32_32x32x16_bf16(vA3, pb3, acc1, 0, 0, 0);
    }
    __builtin_amdgcn_s_setprio(0);
    __syncthreads();   // all waves done reading P(si)

    *(i32x4*)(pwr)        = (i32x4){sd0[0], sd0[1], sd0[2], sd0[3]};
    *(i32x4*)(pwr + 1024) = (i32x4){sd0[4], sd0[5], sd0[6], sd0[7]};
    *(i32x4*)(pwr + 2048) = (i32x4){sd1[0], sd1[1], sd1[2], sd1[3]};
    *(i32x4*)(pwr + 3072) = (i32x4){sd1[4], sd1[5], sd1[6], sd1[7]};
    __syncthreads();   // P(si+1) visible

    kf0 = nk0; kf1 = nk1;
  }

  // hi-partner combine of own-tile column sums
  lrun += __shfl_xor(lrun, 32);

  // ---------------- epilogue ----------------
  float* mlb = (float*)lds;             // [16 waves][64 lanes] (P no longer needed)
  mlb[w * 64 + l] = lrun;
  __syncthreads();
  float L0 = 0.f, L1 = 0.f;
#pragma unroll
  for (int hh = 0; hh < 2; ++hh)
#pragma unroll
    for (int mt = 0; mt < 4; ++mt) {
      L0 += mlb[(hh * 8 + mt * 2 + 0) * 64 + l];
      L1 += mlb[(hh * 8 + mt * 2 + 1) * 64 + l];
    }
  __syncthreads();
  char* xch = lds;                      // [8 u][64 l][128B], swizzled
  const int xbase = (u * 64 + l) * 128;
  if (h == 1) {
#pragma unroll
    for (int i = 0; i < 8; i++) {
      f32x4 v;
#pragma unroll
      for (int r = 0; r < 4; r++) v[r] = (i >> 2) ? acc1[(i & 3) * 4 + r] : acc0[(i & 3) * 4 + r];
      *(f32x4*)(xch + xbase + ((i * 16) ^ ((l & 7) << 4))) = v;
    }
  }
  __syncthreads();
  if (h == 0) {
    const float inv0 = 0.1f / L0;
    const float inv1 = 0.1f / L1;
#pragma unroll
    for (int i = 0; i < 8; i++) {
      f32x4 po = *(const f32x4*)(xch + xbase + ((i * 16) ^ ((l & 7) << 4)));
      const int p_ = i & 3;
      const int ntw = i >> 2;
      const float inv = ntw ? inv1 : inv0;
      const int n = n0 + ntw * 32 + q;
      const int cbase = u * 32 + p_ * 8 + hi * 4;
#pragma unroll
      for (int r = 0; r < 4; r++) {
        const float own = ntw ? acc1[p_ * 4 + r] : acc0[p_ * 4 + r];
        const size_t idx = ((size_t)b * C_ + (cbase + r)) * N_ + n;
        out[idx] = x[idx] + (own + po[r]) * inv;
      }
    }
  }
}

extern "C" void kernel_launch(void* const* d_in, const int* in_sizes, int n_in,
                              void* d_out, int out_size, void* d_ws, size_t ws_size,
                              hipStream_t stream) {
  const float* x  = (const float*)d_in[0];
  const float* w1 = (const float*)d_in[1];
  const float* b1 = (const float*)d_in[2];
  float* out = (float*)d_out;
  short* fT  = (short*)d_ws;                         // [B][N][16] bf16, 512KB
  short* vtP = (short*)((char*)d_ws + 512 * 1024);   // [B][512][256][8] bf16, 8MB
  pre<<<dim3(1024), dim3(256), 0, stream>>>(x, w1, b1, fT, vtP);
  flash17<<<dim3(256), dim3(1024), 0, stream>>>(x, vtP, fT, out);
}